// Round 7
// baseline (177.063 us; speedup 1.0000x reference)
//
#include <hip/hip_runtime.h>

// MCLLoss: masked L1 loss over 5 overlapping value-ranges of real_img.
// Ranges: (-1,1), (-1,-.5), (-.5,0), (0,.5), (.5,1) — inclusive bounds,
// masks overlap; class_mask takes the LAST matching range index.
// Output layout: [loss, losses[5], class_mask_rescaled[N]]; rescale = cls*0.5-1.
//
// R7: R6's dense-store realignment kept (LDS exchange -> every thread does a
// dense 16B-aligned float4 store), but the two R6-only correctness hazards
// removed: no nontemporal hints (suspect for post-timing poison/coherence
// divergence) and ov0/ov1 zero-initialized (unconditional ex[] write read
// them uninitialized when v0/v1 false -> UB). Shape+banked atomics = R5.

#define N_BANKS 64
#define BANK_F  16   // floats per bank (64 B line): sums at [0..4], counts at [8..12]

__device__ __forceinline__ void proc_elem(float pv, float rv,
                                          float s[5], unsigned int c[5],
                                          float& ov) {
    float d = fabsf(pv - rv);
    bool geM1  = rv >= -1.0f;
    bool leM05 = rv <= -0.5f;
    bool geM05 = rv >= -0.5f;
    bool le0   = rv <=  0.0f;
    bool ge0   = rv >=  0.0f;
    bool le05  = rv <=  0.5f;
    bool ge05  = rv >=  0.5f;
    bool le1   = rv <=  1.0f;
    bool in0 = geM1  && le1;
    bool in1 = geM1  && leM05;
    bool in2 = geM05 && le0;
    bool in3 = ge0   && le05;
    bool in4 = ge05  && le1;
    s[0] += in0 ? d : 0.f;  c[0] += in0;
    s[1] += in1 ? d : 0.f;  c[1] += in1;
    s[2] += in2 ? d : 0.f;  c[2] += in2;
    s[3] += in3 ? d : 0.f;  c[3] += in3;
    s[4] += in4 ? d : 0.f;  c[4] += in4;
    int cls = in4 ? 4 : (in3 ? 3 : (in2 ? 2 : (in1 ? 1 : 0)));
    ov = 0.5f * (float)cls - 1.0f;
}

__device__ __forceinline__ void proc4(const float4& p, const float4& r,
                                      float s[5], unsigned int c[5], float ov[4]) {
    proc_elem(p.x, r.x, s, c, ov[0]);
    proc_elem(p.y, r.y, s, c, ov[1]);
    proc_elem(p.z, r.z, s, c, ov[2]);
    proc_elem(p.w, r.w, s, c, ov[3]);
}

__global__ __launch_bounds__(256, 8) void mcl_main(
    const float* __restrict__ pre, const float* __restrict__ real,
    float* __restrict__ mask_out, float* __restrict__ acc, int n4, int n)
{
    float s[5] = {0.f, 0.f, 0.f, 0.f, 0.f};
    unsigned int c[5] = {0u, 0u, 0u, 0u, 0u};

    const int t = threadIdx.x;
    const int i0 = blockIdx.x * 512 + t;   // block covers 512 float4 groups (8 KB)
    const int i1 = i0 + 256;
    const bool v0 = i0 < n4;
    const bool v1 = i1 < n4;

    const float4* pre4  = (const float4*)pre;
    const float4* real4 = (const float4*)real;

    // all four 16B loads upfront (64 B in flight per thread)
    float4 p0, r0, p1, r1;
    if (v0) { p0 = pre4[i0]; r0 = real4[i0]; }
    if (v1) { p1 = pre4[i1]; r1 = real4[i1]; }

    float ov0[4] = {0.f, 0.f, 0.f, 0.f};   // zero-init: ex[] write below is
    float ov1[4] = {0.f, 0.f, 0.f, 0.f};   // unconditional (no UB reads)
    if (v0) proc4(p0, r0, s, c, ov0);
    if (v1) proc4(p1, r1, s, c, ov1);

    // --- store realignment: pass each group's last 2 mask values to the
    // thread owning the NEXT group (slot index = group index within block),
    // so every thread stores a dense 16B-aligned float4 window [4i-2, 4i+2).
    __shared__ float2 ex[512];
    ex[t]       = make_float2(ov0[2], ov0[3]);
    ex[256 + t] = make_float2(ov1[2], ov1[3]);
    __syncthreads();

    if (v0) {
        if (t > 0) {
            float2 pv = ex[t - 1];  // group i0-1's elements 4i0-2, 4i0-1
            float4* w = (float4*)(mask_out + 4 * (size_t)i0 - 2);  // 16B-aligned
            *w = make_float4(pv.x, pv.y, ov0[0], ov0[1]);
        } else {
            // block front edge: elements 4i0, 4i0+1 (8B-aligned)
            float2* w = (float2*)(mask_out + 4 * (size_t)i0);
            *w = make_float2(ov0[0], ov0[1]);
        }
        if (i0 + 1 >= n4) {  // partial-block corner: cover own tail
            float2* w = (float2*)(mask_out + 4 * (size_t)i0 + 2);
            *w = make_float2(ov0[2], ov0[3]);
        }
    }
    if (v1) {
        float2 pv = ex[255 + t];  // group i1-1's elements 4i1-2, 4i1-1
        float4* w = (float4*)(mask_out + 4 * (size_t)i1 - 2);      // 16B-aligned
        *w = make_float4(pv.x, pv.y, ov1[0], ov1[1]);
        if (t == 255 || i1 + 1 >= n4) {  // block back edge: own tail
            float2* w2 = (float2*)(mask_out + 4 * (size_t)i1 + 2);
            *w2 = make_float2(ov1[2], ov1[3]);
        }
    }

    // scalar tail (n not divisible by 4)
    {
        int tail_base = n4 * 4;
        int tail = n - tail_base;
        int gtid = blockIdx.x * blockDim.x + t;
        if (gtid < tail) {
            int idx = tail_base + gtid;
            float ov;
            proc_elem(pre[idx], real[idx], s, c, ov);
            mask_out[idx] = ov;
        }
    }

    // wave64 butterfly reduction
#pragma unroll
    for (int j = 0; j < 5; ++j) {
#pragma unroll
        for (int off = 32; off > 0; off >>= 1) {
            s[j] += __shfl_down(s[j], off, 64);
            c[j] += __shfl_down(c[j], off, 64);
        }
    }

    __shared__ float ls[4][5];
    __shared__ unsigned int lc[4][5];
    int lane = t & 63;
    int wave = t >> 6;
    if (lane == 0) {
#pragma unroll
        for (int j = 0; j < 5; ++j) { ls[wave][j] = s[j]; lc[wave][j] = c[j]; }
    }
    __syncthreads();
    if (t < 5) {
        float ssum = ls[0][t] + ls[1][t] + ls[2][t] + ls[3][t];
        unsigned int csum = lc[0][t] + lc[1][t] + lc[2][t] + lc[3][t];
        float* bank = acc + (blockIdx.x & (N_BANKS - 1)) * BANK_F;
        atomicAdd(&bank[t], ssum);                        // sums at [0..4]
        atomicAdd((unsigned int*)bank + 8 + t, csum);     // counts at [8..12]
    }
}

__global__ void mcl_final(const float* __restrict__ acc, float* __restrict__ out)
{
    // one wave: lane l owns bank l, butterfly-reduce the 10 values
    int l = threadIdx.x;
    const float* bank = acc + l * BANK_F;
    float s[5];
    unsigned int c[5];
#pragma unroll
    for (int j = 0; j < 5; ++j) {
        s[j] = bank[j];
        c[j] = ((const unsigned int*)bank)[8 + j];
    }
#pragma unroll
    for (int j = 0; j < 5; ++j) {
#pragma unroll
        for (int off = 32; off > 0; off >>= 1) {
            s[j] += __shfl_down(s[j], off, 64);
            c[j] += __shfl_down(c[j], off, 64);
        }
    }
    if (l == 0) {
        float total = 0.f;
#pragma unroll
        for (int j = 0; j < 5; ++j) {
            unsigned int cnt = c[j];
            unsigned int denom = cnt > 1u ? cnt : 1u;
            float lv = (cnt == 0u) ? 0.f : (s[j] / (float)denom) * 0.2f;
            out[1 + j] = lv;
            total += lv;
        }
        out[0] = total;
    }
}

extern "C" void kernel_launch(void* const* d_in, const int* in_sizes, int n_in,
                              void* d_out, int out_size, void* d_ws, size_t ws_size,
                              hipStream_t stream) {
    const float* pre  = (const float*)d_in[0];
    const float* real = (const float*)d_in[1];
    float* out = (float*)d_out;
    int n = in_sizes[0];
    int n4 = n / 4;

    float* acc = (float*)d_ws;  // 64 banks x 16 floats = 4 KB

    // d_ws re-poisoned to 0xAA before every timed call — zero each launch.
    (void)hipMemsetAsync(d_ws, 0, N_BANKS * BANK_F * sizeof(float), stream);

    int blocks = (n4 + 511) / 512;                 // 8192 for N=16M
    if (blocks < 1) blocks = 1;
    mcl_main<<<blocks, 256, 0, stream>>>(pre, real, out + 6, acc, n4, n);
    mcl_final<<<1, 64, 0, stream>>>(acc, out);
}